// Round 15
// baseline (124.805 us; speedup 1.0000x reference)
//
#include <hip/hip_runtime.h>

#define NCLS 1024
#define DIM  256
#define NTOT 2048   // 2*NCLS rows in "total"
#define CAP  256    // per-class slot capacity (mean 128, sigma ~11 -> >11 sigma + guard)

typedef short bf16x8 __attribute__((ext_vector_type(8)));
typedef float f32x4  __attribute__((ext_vector_type(4)));

__device__ __forceinline__ float4 f4add(float4 a, float4 b){
  return make_float4(a.x+b.x, a.y+b.y, a.z+b.z, a.w+b.w);
}
__device__ __forceinline__ unsigned short f2bf(float x){   // RNE f32 -> bf16
  unsigned u = __float_as_uint(x);
  return (unsigned short)((u + 0x7FFFu + ((u >> 16) & 1u)) >> 16);
}
__device__ __forceinline__ float bf2f(unsigned short h){
  return __uint_as_float(((unsigned)h) << 16);
}

// ---------------- init: zero per-class cursors ---------------------------------
__global__ void k_init(int* cursor){
  cursor[threadIdx.x] = 0;
}

// ---------------- direct scatter: fixed-capacity class slots -------------------
__global__ __launch_bounds__(256) void k_scatter(const int* __restrict__ tgt, int n,
                                                 int* __restrict__ cursor,
                                                 int* __restrict__ index){
  for (int i = blockIdx.x*blockDim.x + threadIdx.x; i < n; i += gridDim.x*blockDim.x){
    int t = tgt[i];
    int pos = atomicAdd(&cursor[t], 1);
    if (pos < CAP) index[t*CAP + pos] = i;
  }
}

// ---------------- partial gather: 4 blocks per class, NT loads -----------------
// ~2.5 TB/s ceiling = ~60 outstanding 64B lines/CU (MSHR). Final mechanism test:
// nt (non-temporal) cache hint — different L1/L2 allocation path.
__global__ __launch_bounds__(256) void k_gather(const float* __restrict__ xr,
    const float* __restrict__ xi, const int* __restrict__ index,
    const int* __restrict__ cursor, float* __restrict__ Ppart)
{
  int bid = blockIdx.x;
  int cls = bid >> 2;
  int h   = (bid >> 1) & 1;
  int a   = bid & 1;
  int tid = threadIdx.x;
  int l = tid & 63, g = tid >> 6;
  int cnt = cursor[cls]; if (cnt > CAP) cnt = CAP;
  int off = cls*CAP;
  int c0 = (cnt + 1) >> 1;
  int start = off + (h ? c0 : 0);
  int end   = off + (h ? cnt : c0);
  const float* __restrict__ X = a ? xi : xr;
  const float4* __restrict__ X4 = (const float4*)X;

  unsigned lb = (unsigned)l * 16u;
  f32x4 acc = {0.f,0.f,0.f,0.f};
  int j = start + g;
  for (; j + 4 < end; j += 8){
    unsigned o0 = (unsigned)index[j]  *1024u + lb;
    unsigned o1 = (unsigned)index[j+4]*1024u + lb;
    f32x4 v0, v1;
    asm volatile("global_load_dwordx4 %0, %1, %2 nt" : "=v"(v0) : "v"(o0), "s"(X));
    asm volatile("global_load_dwordx4 %0, %1, %2 nt" : "=v"(v1) : "v"(o1), "s"(X));
    asm volatile("s_waitcnt vmcnt(0)" ::: "memory");
    __builtin_amdgcn_sched_barrier(0);
    acc += v0 + v1;
  }
  if (j < end){
    float4 v = X4[(unsigned)index[j]*64u + l];
    acc.x += v.x; acc.y += v.y; acc.z += v.z; acc.w += v.w;
  }

  __shared__ f32x4 sh[256];
  sh[tid] = acc; __syncthreads();
  if (tid < 64){
    f32x4 r = (sh[tid] + sh[tid+64]) + (sh[tid+128] + sh[tid+192]);
    float4 o; o.x = r.x; o.y = r.y; o.z = r.z; o.w = r.w;
    ((float4*)Ppart)[bid*64 + tid] = o;
  }
}

// ------ fused: combine -> T rows + split-bf16 + sq  AND  colsum from Ppart -----
// Blocks 0..511: one wave per (cls,a). Blocks 512..543: column sums from Ppart
// (independent of T -> no intra-dispatch race; verified in R11).
__global__ __launch_bounds__(256) void k_combcol(const float* __restrict__ Ppart,
    const int* __restrict__ cursor, float* __restrict__ T,
    unsigned short* __restrict__ Thi, unsigned short* __restrict__ Tlo,
    float* __restrict__ sq, float* __restrict__ Pcol)
{
  if (blockIdx.x < 512){
    int wv  = blockIdx.x*4 + (threadIdx.x >> 6);   // 0..2047 = cls*2 + a
    int cls = wv >> 1, a = wv & 1;
    int l   = threadIdx.x & 63;
    const float4* P4 = (const float4*)Ppart;
    float4 p0 = P4[(cls*4 + 0 + a)*64 + l];
    float4 p1 = P4[(cls*4 + 2 + a)*64 + l];
    int cnt = cursor[cls]; if (cnt > CAP) cnt = CAP;
    float invd = 1.f / fmaxf((float)cnt, 1.f);
    float4 c;
    c.x = (p0.x + p1.x) * invd;
    c.y = (p0.y + p1.y) * invd;
    c.z = (p0.z + p1.z) * invd;
    c.w = (p0.w + p1.w) * invd;
    int row = a ? (NCLS + cls) : cls;
    ((float4*)T)[row*64 + l] = c;
    ushort4 h4, l4;
    h4.x = f2bf(c.x); l4.x = f2bf(c.x - bf2f(h4.x));
    h4.y = f2bf(c.y); l4.y = f2bf(c.y - bf2f(h4.y));
    h4.z = f2bf(c.z); l4.z = f2bf(c.z - bf2f(h4.z));
    h4.w = f2bf(c.w); l4.w = f2bf(c.w - bf2f(h4.w));
    *(ushort4*)&Thi[row*DIM + l*4] = h4;
    *(ushort4*)&Tlo[row*DIM + l*4] = l4;
    float v = c.x*c.x + c.y*c.y + c.z*c.z + c.w*c.w;
    #pragma unroll
    for (int o = 32; o > 0; o >>= 1) v += __shfl_down(v, o);
    if (l == 0) sq[row] = v;
  } else {
    int b = blockIdx.x - 512;        // 0..31: classes [b*32, b*32+32)
    int t = threadIdx.x;             // dim
    float cs = 0.f;
    for (int cls = b*32; cls < b*32 + 32; ++cls){
      int cnt = cursor[cls]; if (cnt > CAP) cnt = CAP;
      float invd = 1.f / fmaxf((float)cnt, 1.f);
      float s = Ppart[(cls*4+0)*DIM + t] + Ppart[(cls*4+1)*DIM + t]
              + Ppart[(cls*4+2)*DIM + t] + Ppart[(cls*4+3)*DIM + t];
      cs += s * invd;
    }
    Pcol[b*DIM + t] = cs;
  }
}

// ---------------- bandwidth: reduce sq + ||colsum||^2; zero lossacc ------------
// sum(dists) = 2n*sum(sq) - 2*||colsum||^2  (exact f32 path; clamp noise ~1e-6)
__global__ __launch_bounds__(256) void k_bw(const float* __restrict__ sq,
    const float* __restrict__ Pcol, float* __restrict__ invbw,
    double* __restrict__ lossacc){
  int t = threadIdx.x;
  double acc = 0.0;
  for (int i = t; i < NTOT; i += 256) acc += (double)sq[i];
  float cs = 0.f;
  for (int b = 0; b < 32; ++b) cs += Pcol[b*DIM + t];
  double c2 = (double)cs * (double)cs;
  #pragma unroll
  for (int o = 32; o > 0; o >>= 1){
    acc += __shfl_down(acc, o);
    c2  += __shfl_down(c2, o);
  }
  __shared__ double ra[4], rc[4];
  int lane = t & 63, wid = t >> 6;
  if (lane == 0){ ra[wid] = acc; rc[wid] = c2; }
  __syncthreads();
  if (t == 0){
    double S_sq = ra[0]+ra[1]+ra[2]+ra[3];
    double S_cs = rc[0]+rc[1]+rc[2]+rc[3];
    double S1 = 2.0*(double)NTOT*S_sq - 2.0*S_cs;
    double bw = S1 / ((double)NTOT*(double)NTOT - (double)NTOT) / 4.0;
    #pragma unroll
    for (int k = 0; k < 5; ++k)
      invbw[k] = (float)(1.0 / (bw * (double)(1 << k)));
    *lossacc = 0.0;
  }
}

// ------------- MFMA Gram (split-bf16, 3 products) + 5-exp + reduction ----------
// Symmetric: bx>=by only, off-diagonal x2. 64x64 tile, 4 waves, m89 layouts.
__global__ __launch_bounds__(256) void k_mmd(
    const unsigned short* __restrict__ Thi, const unsigned short* __restrict__ Tlo,
    const float* __restrict__ sq, const float* __restrict__ invbw,
    double* __restrict__ lossacc)
{
  int bx = blockIdx.x, by = blockIdx.y;
  if (bx < by) return;
  __shared__ unsigned short Ah[64][40], Al[64][40], Bh[64][40], Bl[64][40];
  __shared__ float red[4];
  int tid = threadIdx.x;
  int w = tid >> 6, l = tid & 63;
  int rowA = by*64, rowB = bx*64;
  f32x4 acc[4];
  #pragma unroll
  for (int t = 0; t < 4; ++t) acc[t] = (f32x4){0.f,0.f,0.f,0.f};

  int srow = tid >> 2, sseg = (tid & 3)*8;
  int ar = w*16 + (l & 15);
  int kg = (l >> 4)*8;

  for (int kk = 0; kk < DIM; kk += 32){
    __syncthreads();
    *(bf16x8*)&Ah[srow][sseg] = *(const bf16x8*)&Thi[(rowA+srow)*DIM + kk + sseg];
    *(bf16x8*)&Al[srow][sseg] = *(const bf16x8*)&Tlo[(rowA+srow)*DIM + kk + sseg];
    *(bf16x8*)&Bh[srow][sseg] = *(const bf16x8*)&Thi[(rowB+srow)*DIM + kk + sseg];
    *(bf16x8*)&Bl[srow][sseg] = *(const bf16x8*)&Tlo[(rowB+srow)*DIM + kk + sseg];
    __syncthreads();
    bf16x8 ah = *(const bf16x8*)&Ah[ar][kg];
    bf16x8 al = *(const bf16x8*)&Al[ar][kg];
    #pragma unroll
    for (int t = 0; t < 4; ++t){
      int br = t*16 + (l & 15);
      bf16x8 bh = *(const bf16x8*)&Bh[br][kg];
      bf16x8 bl = *(const bf16x8*)&Bl[br][kg];
      acc[t] = __builtin_amdgcn_mfma_f32_16x16x32_bf16(ah, bh, acc[t], 0, 0, 0);
      acc[t] = __builtin_amdgcn_mfma_f32_16x16x32_bf16(ah, bl, acc[t], 0, 0, 0);
      acc[t] = __builtin_amdgcn_mfma_f32_16x16x32_bf16(al, bh, acc[t], 0, 0, 0);
    }
  }

  float i0 = invbw[0], i1 = invbw[1], i2 = invbw[2], i3 = invbw[3], i4 = invbw[4];
  float wgt = (bx > by) ? 2.f : 1.f;
  float lacc = 0.f;
  int ibase = rowA + w*16 + ((l >> 4)*4);
  float sqi[4]; float sgnI[4];
  #pragma unroll
  for (int r = 0; r < 4; ++r){
    int i = ibase + r;
    sqi[r]  = sq[i];
    sgnI[r] = (i < NCLS) ? 1.f : -1.f;
  }
  #pragma unroll
  for (int t = 0; t < 4; ++t){
    int j = rowB + t*16 + (l & 15);
    float sqj = sq[j];
    bool jn = (j < NCLS);
    #pragma unroll
    for (int r = 0; r < 4; ++r){
      float d = sqi[r] + sqj - 2.f*acc[t][r];
      d = fmaxf(d, 0.f);
      float ws = __expf(-d*i0) + __expf(-d*i1) + __expf(-d*i2) + __expf(-d*i3) + __expf(-d*i4);
      lacc += (jn ? sgnI[r] : -sgnI[r]) * ws;
    }
  }
  lacc *= wgt;
  #pragma unroll
  for (int o = 32; o > 0; o >>= 1) lacc += __shfl_down(lacc, o);
  if (l == 0) red[w] = lacc;
  __syncthreads();
  if (tid == 0) atomicAdd(lossacc, (double)(red[0]+red[1]+red[2]+red[3]));
}

__global__ void k_final(const double* __restrict__ lossacc, float* __restrict__ out){
  out[0] = (float)(*lossacc * (1.0 / ((double)NCLS * (double)NCLS)));
}

extern "C" void kernel_launch(void* const* d_in, const int* in_sizes, int n_in,
                              void* d_out, int out_size, void* d_ws, size_t ws_size,
                              hipStream_t stream) {
  const float* xr  = (const float*)d_in[0];
  const float* xi  = (const float*)d_in[1];
  const int*   tgt = (const int*)d_in[2];
  float* out = (float*)d_out;
  int n = in_sizes[2];                 // 131072 rows

  char* w = (char*)d_ws;
  int* cursor   = (int*)w;                      // 1024 (doubles as counts)
  int* index    = cursor + NCLS;                // 1024*CAP
  float* T      = (float*)(index + NCLS*CAP);   // 2048*256 f32
  float* sq     = T + NTOT*DIM;                 // 2048
  float* invbw  = sq + NTOT;                    // 5 (+3 pad)
  double* lossd = (double*)(invbw + 8);         // 1
  float* Ppart  = (float*)(lossd + 1);          // 4096*256 = 4 MB
  float* Pcol   = Ppart + 4*NCLS*DIM;           // 32*256
  unsigned short* Thi = (unsigned short*)(Pcol + 32*DIM);  // 2048*256 bf16
  unsigned short* Tlo = Thi + NTOT*DIM;                    // 2048*256 bf16

  k_init<<<1, 1024, 0, stream>>>(cursor);
  k_scatter<<<256, 256, 0, stream>>>(tgt, n, cursor, index);
  k_gather<<<4*NCLS, 256, 0, stream>>>(xr, xi, index, cursor, Ppart);
  k_combcol<<<544, 256, 0, stream>>>(Ppart, cursor, T, Thi, Tlo, sq, Pcol);
  k_bw<<<1, 256, 0, stream>>>(sq, Pcol, invbw, lossd);
  k_mmd<<<dim3(32, 32), 256, 0, stream>>>(Thi, Tlo, sq, invbw, lossd);
  k_final<<<1, 1, 0, stream>>>(lossd, out);
}

// Round 16
// 119.785 us; speedup vs baseline: 1.0419x; 1.0419x over previous
//
#include <hip/hip_runtime.h>

#define NCLS 1024
#define DIM  256
#define NTOT 2048   // 2*NCLS rows in "total"
#define CAP  256    // per-class slot capacity (mean 128, sigma ~11 -> >11 sigma + guard)

typedef short bf16x8 __attribute__((ext_vector_type(8)));
typedef float f32x4  __attribute__((ext_vector_type(4)));

__device__ __forceinline__ float4 f4add(float4 a, float4 b){
  return make_float4(a.x+b.x, a.y+b.y, a.z+b.z, a.w+b.w);
}
__device__ __forceinline__ unsigned short f2bf(float x){   // RNE f32 -> bf16
  unsigned u = __float_as_uint(x);
  return (unsigned short)((u + 0x7FFFu + ((u >> 16) & 1u)) >> 16);
}
__device__ __forceinline__ float bf2f(unsigned short h){
  return __uint_as_float(((unsigned)h) << 16);
}

// ---------------- init: zero per-class cursors ---------------------------------
__global__ void k_init(int* cursor){
  cursor[threadIdx.x] = 0;
}

// ---------------- direct scatter: fixed-capacity class slots -------------------
__global__ __launch_bounds__(256) void k_scatter(const int* __restrict__ tgt, int n,
                                                 int* __restrict__ cursor,
                                                 int* __restrict__ index){
  for (int i = blockIdx.x*blockDim.x + threadIdx.x; i < n; i += gridDim.x*blockDim.x){
    int t = tgt[i];
    int pos = atomicAdd(&cursor[t], 1);
    if (pos < CAP) index[t*CAP + pos] = i;
  }
}

// ---------------- partial gather: 4 blocks per class ---------------------------
// Plain compiler-scheduled loads — the proven 105-108us form (R13/R14).
// At the ~2.5 TB/s random-1KB ceiling (~60 outstanding 64B lines/CU MSHR limit;
// mechanism-invariant R6/R8/R9, residency-invariant R10, nt hint HURTS R15).
__global__ __launch_bounds__(256) void k_gather(const float* __restrict__ xr,
    const float* __restrict__ xi, const int* __restrict__ index,
    const int* __restrict__ cursor, float* __restrict__ Ppart)
{
  int bid = blockIdx.x;
  int cls = bid >> 2;
  int h   = (bid >> 1) & 1;
  int a   = bid & 1;
  int tid = threadIdx.x;
  int l = tid & 63, g = tid >> 6;
  int cnt = cursor[cls]; if (cnt > CAP) cnt = CAP;
  int off = cls*CAP;
  int c0 = (cnt + 1) >> 1;
  int start = off + (h ? c0 : 0);
  int end   = off + (h ? cnt : c0);
  const float4* __restrict__ X4 = (const float4*)(a ? xi : xr);

  float4 s0 = make_float4(0,0,0,0), s1 = make_float4(0,0,0,0);
  int j = start + g;
  for (; j + 4 < end; j += 8){
    unsigned r0 = (unsigned)index[j];
    unsigned r1 = (unsigned)index[j+4];
    float4 v0 = X4[r0*64u + l];
    float4 v1 = X4[r1*64u + l];
    s0 = f4add(s0, v0);
    s1 = f4add(s1, v1);
  }
  if (j < end) s0 = f4add(s0, X4[(unsigned)index[j]*64u + l]);
  s0 = f4add(s0, s1);

  __shared__ float4 sh[256];
  sh[tid] = s0; __syncthreads();
  if (tid < 64){
    float4 r = f4add(f4add(sh[tid], sh[tid+64]), f4add(sh[tid+128], sh[tid+192]));
    ((float4*)Ppart)[bid*64 + tid] = r;
  }
}

// ------ fused: combine -> T rows + split-bf16 + sq  AND  colsum from Ppart -----
// Blocks 0..511: one wave per (cls,a). Blocks 512..543: column sums from Ppart
// (independent of T -> no intra-dispatch race).
__global__ __launch_bounds__(256) void k_combcol(const float* __restrict__ Ppart,
    const int* __restrict__ cursor, float* __restrict__ T,
    unsigned short* __restrict__ Thi, unsigned short* __restrict__ Tlo,
    float* __restrict__ sq, float* __restrict__ Pcol)
{
  if (blockIdx.x < 512){
    int wv  = blockIdx.x*4 + (threadIdx.x >> 6);   // 0..2047 = cls*2 + a
    int cls = wv >> 1, a = wv & 1;
    int l   = threadIdx.x & 63;
    const float4* P4 = (const float4*)Ppart;
    float4 p0 = P4[(cls*4 + 0 + a)*64 + l];
    float4 p1 = P4[(cls*4 + 2 + a)*64 + l];
    int cnt = cursor[cls]; if (cnt > CAP) cnt = CAP;
    float invd = 1.f / fmaxf((float)cnt, 1.f);
    float4 c;
    c.x = (p0.x + p1.x) * invd;
    c.y = (p0.y + p1.y) * invd;
    c.z = (p0.z + p1.z) * invd;
    c.w = (p0.w + p1.w) * invd;
    int row = a ? (NCLS + cls) : cls;
    ((float4*)T)[row*64 + l] = c;
    ushort4 h4, l4;
    h4.x = f2bf(c.x); l4.x = f2bf(c.x - bf2f(h4.x));
    h4.y = f2bf(c.y); l4.y = f2bf(c.y - bf2f(h4.y));
    h4.z = f2bf(c.z); l4.z = f2bf(c.z - bf2f(h4.z));
    h4.w = f2bf(c.w); l4.w = f2bf(c.w - bf2f(h4.w));
    *(ushort4*)&Thi[row*DIM + l*4] = h4;
    *(ushort4*)&Tlo[row*DIM + l*4] = l4;
    float v = c.x*c.x + c.y*c.y + c.z*c.z + c.w*c.w;
    #pragma unroll
    for (int o = 32; o > 0; o >>= 1) v += __shfl_down(v, o);
    if (l == 0) sq[row] = v;
  } else {
    int b = blockIdx.x - 512;        // 0..31: classes [b*32, b*32+32)
    int t = threadIdx.x;             // dim
    float cs = 0.f;
    for (int cls = b*32; cls < b*32 + 32; ++cls){
      int cnt = cursor[cls]; if (cnt > CAP) cnt = CAP;
      float invd = 1.f / fmaxf((float)cnt, 1.f);
      float s = Ppart[(cls*4+0)*DIM + t] + Ppart[(cls*4+1)*DIM + t]
              + Ppart[(cls*4+2)*DIM + t] + Ppart[(cls*4+3)*DIM + t];
      cs += s * invd;
    }
    Pcol[b*DIM + t] = cs;
  }
}

// ---------------- bandwidth: reduce sq + ||colsum||^2; zero lossacc ------------
// sum(dists) = 2n*sum(sq) - 2*||colsum||^2  (exact f32 path; clamp noise ~1e-6)
__global__ __launch_bounds__(256) void k_bw(const float* __restrict__ sq,
    const float* __restrict__ Pcol, float* __restrict__ invbw,
    double* __restrict__ lossacc){
  int t = threadIdx.x;
  double acc = 0.0;
  for (int i = t; i < NTOT; i += 256) acc += (double)sq[i];
  float cs = 0.f;
  for (int b = 0; b < 32; ++b) cs += Pcol[b*DIM + t];
  double c2 = (double)cs * (double)cs;
  #pragma unroll
  for (int o = 32; o > 0; o >>= 1){
    acc += __shfl_down(acc, o);
    c2  += __shfl_down(c2, o);
  }
  __shared__ double ra[4], rc[4];
  int lane = t & 63, wid = t >> 6;
  if (lane == 0){ ra[wid] = acc; rc[wid] = c2; }
  __syncthreads();
  if (t == 0){
    double S_sq = ra[0]+ra[1]+ra[2]+ra[3];
    double S_cs = rc[0]+rc[1]+rc[2]+rc[3];
    double S1 = 2.0*(double)NTOT*S_sq - 2.0*S_cs;
    double bw = S1 / ((double)NTOT*(double)NTOT - (double)NTOT) / 4.0;
    #pragma unroll
    for (int k = 0; k < 5; ++k)
      invbw[k] = (float)(1.0 / (bw * (double)(1 << k)));
    *lossacc = 0.0;
  }
}

// ------------- MFMA Gram (split-bf16, 3 products) + 5-exp + reduction ----------
// Symmetric: bx>=by only, off-diagonal x2. 64x64 tile, 4 waves, m89 layouts.
__global__ __launch_bounds__(256) void k_mmd(
    const unsigned short* __restrict__ Thi, const unsigned short* __restrict__ Tlo,
    const float* __restrict__ sq, const float* __restrict__ invbw,
    double* __restrict__ lossacc)
{
  int bx = blockIdx.x, by = blockIdx.y;
  if (bx < by) return;
  __shared__ unsigned short Ah[64][40], Al[64][40], Bh[64][40], Bl[64][40];
  __shared__ float red[4];
  int tid = threadIdx.x;
  int w = tid >> 6, l = tid & 63;
  int rowA = by*64, rowB = bx*64;
  f32x4 acc[4];
  #pragma unroll
  for (int t = 0; t < 4; ++t) acc[t] = (f32x4){0.f,0.f,0.f,0.f};

  int srow = tid >> 2, sseg = (tid & 3)*8;
  int ar = w*16 + (l & 15);
  int kg = (l >> 4)*8;

  for (int kk = 0; kk < DIM; kk += 32){
    __syncthreads();
    *(bf16x8*)&Ah[srow][sseg] = *(const bf16x8*)&Thi[(rowA+srow)*DIM + kk + sseg];
    *(bf16x8*)&Al[srow][sseg] = *(const bf16x8*)&Tlo[(rowA+srow)*DIM + kk + sseg];
    *(bf16x8*)&Bh[srow][sseg] = *(const bf16x8*)&Thi[(rowB+srow)*DIM + kk + sseg];
    *(bf16x8*)&Bl[srow][sseg] = *(const bf16x8*)&Tlo[(rowB+srow)*DIM + kk + sseg];
    __syncthreads();
    bf16x8 ah = *(const bf16x8*)&Ah[ar][kg];
    bf16x8 al = *(const bf16x8*)&Al[ar][kg];
    #pragma unroll
    for (int t = 0; t < 4; ++t){
      int br = t*16 + (l & 15);
      bf16x8 bh = *(const bf16x8*)&Bh[br][kg];
      bf16x8 bl = *(const bf16x8*)&Bl[br][kg];
      acc[t] = __builtin_amdgcn_mfma_f32_16x16x32_bf16(ah, bh, acc[t], 0, 0, 0);
      acc[t] = __builtin_amdgcn_mfma_f32_16x16x32_bf16(ah, bl, acc[t], 0, 0, 0);
      acc[t] = __builtin_amdgcn_mfma_f32_16x16x32_bf16(al, bh, acc[t], 0, 0, 0);
    }
  }

  float i0 = invbw[0], i1 = invbw[1], i2 = invbw[2], i3 = invbw[3], i4 = invbw[4];
  float wgt = (bx > by) ? 2.f : 1.f;
  float lacc = 0.f;
  int ibase = rowA + w*16 + ((l >> 4)*4);
  float sqi[4]; float sgnI[4];
  #pragma unroll
  for (int r = 0; r < 4; ++r){
    int i = ibase + r;
    sqi[r]  = sq[i];
    sgnI[r] = (i < NCLS) ? 1.f : -1.f;
  }
  #pragma unroll
  for (int t = 0; t < 4; ++t){
    int j = rowB + t*16 + (l & 15);
    float sqj = sq[j];
    bool jn = (j < NCLS);
    #pragma unroll
    for (int r = 0; r < 4; ++r){
      float d = sqi[r] + sqj - 2.f*acc[t][r];
      d = fmaxf(d, 0.f);
      float ws = __expf(-d*i0) + __expf(-d*i1) + __expf(-d*i2) + __expf(-d*i3) + __expf(-d*i4);
      lacc += (jn ? sgnI[r] : -sgnI[r]) * ws;
    }
  }
  lacc *= wgt;
  #pragma unroll
  for (int o = 32; o > 0; o >>= 1) lacc += __shfl_down(lacc, o);
  if (l == 0) red[w] = lacc;
  __syncthreads();
  if (tid == 0) atomicAdd(lossacc, (double)(red[0]+red[1]+red[2]+red[3]));
}

__global__ void k_final(const double* __restrict__ lossacc, float* __restrict__ out){
  out[0] = (float)(*lossacc * (1.0 / ((double)NCLS * (double)NCLS)));
}

extern "C" void kernel_launch(void* const* d_in, const int* in_sizes, int n_in,
                              void* d_out, int out_size, void* d_ws, size_t ws_size,
                              hipStream_t stream) {
  const float* xr  = (const float*)d_in[0];
  const float* xi  = (const float*)d_in[1];
  const int*   tgt = (const int*)d_in[2];
  float* out = (float*)d_out;
  int n = in_sizes[2];                 // 131072 rows

  char* w = (char*)d_ws;
  int* cursor   = (int*)w;                      // 1024 (doubles as counts)
  int* index    = cursor + NCLS;                // 1024*CAP
  float* T      = (float*)(index + NCLS*CAP);   // 2048*256 f32
  float* sq     = T + NTOT*DIM;                 // 2048
  float* invbw  = sq + NTOT;                    // 5 (+3 pad)
  double* lossd = (double*)(invbw + 8);         // 1
  float* Ppart  = (float*)(lossd + 1);          // 4096*256 = 4 MB
  float* Pcol   = Ppart + 4*NCLS*DIM;           // 32*256
  unsigned short* Thi = (unsigned short*)(Pcol + 32*DIM);  // 2048*256 bf16
  unsigned short* Tlo = Thi + NTOT*DIM;                    // 2048*256 bf16

  k_init<<<1, 1024, 0, stream>>>(cursor);
  k_scatter<<<256, 256, 0, stream>>>(tgt, n, cursor, index);
  k_gather<<<4*NCLS, 256, 0, stream>>>(xr, xi, index, cursor, Ppart);
  k_combcol<<<544, 256, 0, stream>>>(Ppart, cursor, T, Thi, Tlo, sq, Pcol);
  k_bw<<<1, 256, 0, stream>>>(sq, Pcol, invbw, lossd);
  k_mmd<<<dim3(32, 32), 256, 0, stream>>>(Thi, Tlo, sq, invbw, lossd);
  k_final<<<1, 1, 0, stream>>>(lossd, out);
}

// Round 17
// 117.366 us; speedup vs baseline: 1.0634x; 1.0206x over previous
//
#include <hip/hip_runtime.h>

#define NCLS 1024
#define DIM  256
#define NTOT 2048   // 2*NCLS rows in "total"
#define CAP  256    // per-class slot capacity (mean 128, sigma ~11 -> >11 sigma + guard)

typedef short bf16x8 __attribute__((ext_vector_type(8)));
typedef float f32x4  __attribute__((ext_vector_type(4)));

__device__ __forceinline__ float4 f4add(float4 a, float4 b){
  return make_float4(a.x+b.x, a.y+b.y, a.z+b.z, a.w+b.w);
}
__device__ __forceinline__ unsigned short f2bf(float x){   // RNE f32 -> bf16
  unsigned u = __float_as_uint(x);
  return (unsigned short)((u + 0x7FFFu + ((u >> 16) & 1u)) >> 16);
}
__device__ __forceinline__ float bf2f(unsigned short h){
  return __uint_as_float(((unsigned)h) << 16);
}

// ---------------- direct scatter: fixed-capacity class slots -------------------
__global__ __launch_bounds__(256) void k_scatter(const int* __restrict__ tgt, int n,
                                                 int* __restrict__ cursor,
                                                 int* __restrict__ index){
  for (int i = blockIdx.x*blockDim.x + threadIdx.x; i < n; i += gridDim.x*blockDim.x){
    int t = tgt[i];
    int pos = atomicAdd(&cursor[t], 1);
    if (pos < CAP) index[t*CAP + pos] = i;
  }
}

// ---------------- partial gather: 4 blocks per class ---------------------------
// Plain compiler-scheduled loads — the proven 104-108us form (R13/R14/R16).
// At the ~2.5 TB/s random-1KB ceiling: ~60 outstanding 64B lines/CU (L1 MSHR),
// invariant across 4 load mechanisms (R6/R8/R9/R15-nt), cold/warm residency.
__global__ __launch_bounds__(256) void k_gather(const float* __restrict__ xr,
    const float* __restrict__ xi, const int* __restrict__ index,
    const int* __restrict__ cursor, float* __restrict__ Ppart)
{
  int bid = blockIdx.x;
  int cls = bid >> 2;
  int h   = (bid >> 1) & 1;
  int a   = bid & 1;
  int tid = threadIdx.x;
  int l = tid & 63, g = tid >> 6;
  int cnt = cursor[cls]; if (cnt > CAP) cnt = CAP;
  int off = cls*CAP;
  int c0 = (cnt + 1) >> 1;
  int start = off + (h ? c0 : 0);
  int end   = off + (h ? cnt : c0);
  const float4* __restrict__ X4 = (const float4*)(a ? xi : xr);

  float4 s0 = make_float4(0,0,0,0), s1 = make_float4(0,0,0,0);
  int j = start + g;
  for (; j + 4 < end; j += 8){
    unsigned r0 = (unsigned)index[j];
    unsigned r1 = (unsigned)index[j+4];
    float4 v0 = X4[r0*64u + l];
    float4 v1 = X4[r1*64u + l];
    s0 = f4add(s0, v0);
    s1 = f4add(s1, v1);
  }
  if (j < end) s0 = f4add(s0, X4[(unsigned)index[j]*64u + l]);
  s0 = f4add(s0, s1);

  __shared__ float4 sh[256];
  sh[tid] = s0; __syncthreads();
  if (tid < 64){
    float4 r = f4add(f4add(sh[tid], sh[tid+64]), f4add(sh[tid+128], sh[tid+192]));
    ((float4*)Ppart)[bid*64 + tid] = r;
  }
}

// ------- combine partials -> T rows + split-bf16 (Thi/Tlo) + sq ----------------
__global__ __launch_bounds__(256) void k_combine(const float* __restrict__ Ppart,
    const int* __restrict__ cursor, float* __restrict__ T,
    unsigned short* __restrict__ Thi, unsigned short* __restrict__ Tlo,
    float* __restrict__ sq)
{
  int wv  = blockIdx.x*4 + (threadIdx.x >> 6);   // 0..2047 = cls*2 + a
  int cls = wv >> 1, a = wv & 1;
  int l   = threadIdx.x & 63;
  const float4* P4 = (const float4*)Ppart;
  float4 p0 = P4[(cls*4 + 0 + a)*64 + l];
  float4 p1 = P4[(cls*4 + 2 + a)*64 + l];
  int cnt = cursor[cls]; if (cnt > CAP) cnt = CAP;
  float invd = 1.f / fmaxf((float)cnt, 1.f);
  float4 c;
  c.x = (p0.x + p1.x) * invd;
  c.y = (p0.y + p1.y) * invd;
  c.z = (p0.z + p1.z) * invd;
  c.w = (p0.w + p1.w) * invd;
  int row = a ? (NCLS + cls) : cls;
  ((float4*)T)[row*64 + l] = c;
  ushort4 h4, l4;
  h4.x = f2bf(c.x); l4.x = f2bf(c.x - bf2f(h4.x));
  h4.y = f2bf(c.y); l4.y = f2bf(c.y - bf2f(h4.y));
  h4.z = f2bf(c.z); l4.z = f2bf(c.z - bf2f(h4.z));
  h4.w = f2bf(c.w); l4.w = f2bf(c.w - bf2f(h4.w));
  *(ushort4*)&Thi[row*DIM + l*4] = h4;
  *(ushort4*)&Tlo[row*DIM + l*4] = l4;
  float v = c.x*c.x + c.y*c.y + c.z*c.z + c.w*c.w;
  #pragma unroll
  for (int o = 32; o > 0; o >>= 1) v += __shfl_down(v, o);
  if (l == 0) sq[row] = v;
}

// ---------------- column-sum partials of T (NO atomics) ------------------------
__global__ __launch_bounds__(256) void k_colsum(const float* __restrict__ T,
                                                float* __restrict__ Pcol){
  int b = blockIdx.x;
  int tid = threadIdx.x;
  int l = tid & 63, g = tid >> 6;
  const float4* T4 = (const float4*)T;
  float4 acc = make_float4(0,0,0,0);
  for (int r = b*64 + g; r < b*64 + 64; r += 4)
    acc = f4add(acc, T4[r*64 + l]);
  __shared__ float4 sh[256];
  sh[tid] = acc; __syncthreads();
  if (tid < 64){
    float4 r = f4add(f4add(sh[tid], sh[tid+64]), f4add(sh[tid+128], sh[tid+192]));
    ((float4*)Pcol)[b*64 + tid] = r;
  }
}

// ---------------- bandwidth: reduce sq + ||colsum||^2; zero lossacc ------------
// sum(dists) = 2n*sum(sq) - 2*||colsum||^2  (exact f32 path; clamp noise ~1e-6)
__global__ __launch_bounds__(256) void k_bw(const float* __restrict__ sq,
    const float* __restrict__ Pcol, float* __restrict__ invbw,
    double* __restrict__ lossacc){
  int t = threadIdx.x;
  double acc = 0.0;
  for (int i = t; i < NTOT; i += 256) acc += (double)sq[i];
  float cs = 0.f;
  for (int b = 0; b < 32; ++b) cs += Pcol[b*DIM + t];
  double c2 = (double)cs * (double)cs;
  #pragma unroll
  for (int o = 32; o > 0; o >>= 1){
    acc += __shfl_down(acc, o);
    c2  += __shfl_down(c2, o);
  }
  __shared__ double ra[4], rc[4];
  int lane = t & 63, wid = t >> 6;
  if (lane == 0){ ra[wid] = acc; rc[wid] = c2; }
  __syncthreads();
  if (t == 0){
    double S_sq = ra[0]+ra[1]+ra[2]+ra[3];
    double S_cs = rc[0]+rc[1]+rc[2]+rc[3];
    double S1 = 2.0*(double)NTOT*S_sq - 2.0*S_cs;
    double bw = S1 / ((double)NTOT*(double)NTOT - (double)NTOT) / 4.0;
    #pragma unroll
    for (int k = 0; k < 5; ++k)
      invbw[k] = (float)(1.0 / (bw * (double)(1 << k)));
    *lossacc = 0.0;
  }
}

// ------------- MFMA Gram (split-bf16, 3 products) + 5-exp + reduction ----------
// Symmetric: bx>=by only, off-diagonal x2. 64x64 tile, 4 waves, m89 layouts.
__global__ __launch_bounds__(256) void k_mmd(
    const unsigned short* __restrict__ Thi, const unsigned short* __restrict__ Tlo,
    const float* __restrict__ sq, const float* __restrict__ invbw,
    double* __restrict__ lossacc)
{
  int bx = blockIdx.x, by = blockIdx.y;
  if (bx < by) return;
  __shared__ unsigned short Ah[64][40], Al[64][40], Bh[64][40], Bl[64][40];
  __shared__ float red[4];
  int tid = threadIdx.x;
  int w = tid >> 6, l = tid & 63;
  int rowA = by*64, rowB = bx*64;
  f32x4 acc[4];
  #pragma unroll
  for (int t = 0; t < 4; ++t) acc[t] = (f32x4){0.f,0.f,0.f,0.f};

  int srow = tid >> 2, sseg = (tid & 3)*8;
  int ar = w*16 + (l & 15);
  int kg = (l >> 4)*8;

  for (int kk = 0; kk < DIM; kk += 32){
    __syncthreads();
    *(bf16x8*)&Ah[srow][sseg] = *(const bf16x8*)&Thi[(rowA+srow)*DIM + kk + sseg];
    *(bf16x8*)&Al[srow][sseg] = *(const bf16x8*)&Tlo[(rowA+srow)*DIM + kk + sseg];
    *(bf16x8*)&Bh[srow][sseg] = *(const bf16x8*)&Thi[(rowB+srow)*DIM + kk + sseg];
    *(bf16x8*)&Bl[srow][sseg] = *(const bf16x8*)&Tlo[(rowB+srow)*DIM + kk + sseg];
    __syncthreads();
    bf16x8 ah = *(const bf16x8*)&Ah[ar][kg];
    bf16x8 al = *(const bf16x8*)&Al[ar][kg];
    #pragma unroll
    for (int t = 0; t < 4; ++t){
      int br = t*16 + (l & 15);
      bf16x8 bh = *(const bf16x8*)&Bh[br][kg];
      bf16x8 bl = *(const bf16x8*)&Bl[br][kg];
      acc[t] = __builtin_amdgcn_mfma_f32_16x16x32_bf16(ah, bh, acc[t], 0, 0, 0);
      acc[t] = __builtin_amdgcn_mfma_f32_16x16x32_bf16(ah, bl, acc[t], 0, 0, 0);
      acc[t] = __builtin_amdgcn_mfma_f32_16x16x32_bf16(al, bh, acc[t], 0, 0, 0);
    }
  }

  float i0 = invbw[0], i1 = invbw[1], i2 = invbw[2], i3 = invbw[3], i4 = invbw[4];
  float wgt = (bx > by) ? 2.f : 1.f;
  float lacc = 0.f;
  int ibase = rowA + w*16 + ((l >> 4)*4);
  float sqi[4]; float sgnI[4];
  #pragma unroll
  for (int r = 0; r < 4; ++r){
    int i = ibase + r;
    sqi[r]  = sq[i];
    sgnI[r] = (i < NCLS) ? 1.f : -1.f;
  }
  #pragma unroll
  for (int t = 0; t < 4; ++t){
    int j = rowB + t*16 + (l & 15);
    float sqj = sq[j];
    bool jn = (j < NCLS);
    #pragma unroll
    for (int r = 0; r < 4; ++r){
      float d = sqi[r] + sqj - 2.f*acc[t][r];
      d = fmaxf(d, 0.f);
      float ws = __expf(-d*i0) + __expf(-d*i1) + __expf(-d*i2) + __expf(-d*i3) + __expf(-d*i4);
      lacc += (jn ? sgnI[r] : -sgnI[r]) * ws;
    }
  }
  lacc *= wgt;
  #pragma unroll
  for (int o = 32; o > 0; o >>= 1) lacc += __shfl_down(lacc, o);
  if (l == 0) red[w] = lacc;
  __syncthreads();
  if (tid == 0) atomicAdd(lossacc, (double)(red[0]+red[1]+red[2]+red[3]));
}

__global__ void k_final(const double* __restrict__ lossacc, float* __restrict__ out){
  out[0] = (float)(*lossacc * (1.0 / ((double)NCLS * (double)NCLS)));
}

extern "C" void kernel_launch(void* const* d_in, const int* in_sizes, int n_in,
                              void* d_out, int out_size, void* d_ws, size_t ws_size,
                              hipStream_t stream) {
  const float* xr  = (const float*)d_in[0];
  const float* xi  = (const float*)d_in[1];
  const int*   tgt = (const int*)d_in[2];
  float* out = (float*)d_out;
  int n = in_sizes[2];                 // 131072 rows

  char* w = (char*)d_ws;
  int* cursor   = (int*)w;                      // 1024 (doubles as counts)
  int* index    = cursor + NCLS;                // 1024*CAP
  float* T      = (float*)(index + NCLS*CAP);   // 2048*256 f32
  float* sq     = T + NTOT*DIM;                 // 2048
  float* invbw  = sq + NTOT;                    // 5 (+3 pad)
  double* lossd = (double*)(invbw + 8);         // 1
  float* Ppart  = (float*)(lossd + 1);          // 4096*256 = 4 MB
  float* Pcol   = Ppart + 4*NCLS*DIM;           // 32*256
  unsigned short* Thi = (unsigned short*)(Pcol + 32*DIM);  // 2048*256 bf16
  unsigned short* Tlo = Thi + NTOT*DIM;                    // 2048*256 bf16

  hipMemsetAsync(cursor, 0, NCLS*sizeof(int), stream);     // replaces k_init launch
  k_scatter<<<256, 256, 0, stream>>>(tgt, n, cursor, index);
  k_gather<<<4*NCLS, 256, 0, stream>>>(xr, xi, index, cursor, Ppart);
  k_combine<<<NTOT/4, 256, 0, stream>>>(Ppart, cursor, T, Thi, Tlo, sq);
  k_colsum<<<32, 256, 0, stream>>>(T, Pcol);
  k_bw<<<1, 256, 0, stream>>>(sq, Pcol, invbw, lossd);
  k_mmd<<<dim3(32, 32), 256, 0, stream>>>(Thi, Tlo, sq, invbw, lossd);
  k_final<<<1, 1, 0, stream>>>(lossd, out);
}